// Round 6
// baseline (318.977 us; speedup 1.0000x reference)
//
#include <hip/hip_runtime.h>
#include <math.h>

#define WS_ 8
#define NH_ 8
#define C_ 256
#define B_ 8
#define M_ 32768            // B_*L_
#define SH_ 4               // WS_/2
#define LN_EPS 1e-5f
#define SL_ 8388608         // elements per [M,C] slot

typedef __attribute__((ext_vector_type(8))) short bf16x8;
typedef __attribute__((ext_vector_type(4))) float f32x4;

__device__ inline float b2f(unsigned short u) {
    union { unsigned int i; float f; } c; c.i = ((unsigned int)u) << 16; return c.f;
}
__device__ inline unsigned short f2b(float f) {
    union { unsigned int i; float f; } c; c.f = f;
    unsigned int u = c.i;
    return (unsigned short)((u + 0x7FFFu + ((u >> 16) & 1u)) >> 16);
}
__device__ inline float gelu_f(float x) {
    // tanh-form GELU: x * sigmoid(1.59576912*(x + 0.044715 x^3)); |err| < ~1e-3
    float t = 1.59576912160573f * (x + 0.044715f * x * x * x);
    return x / (1.f + __expf(-t));
}

// ---------------- AdaLN: ss = t_embed @ w + b --------------------------------
__global__ void adaln_k(const float* __restrict__ te,
                        const float* __restrict__ w1, const float* __restrict__ b1,
                        const float* __restrict__ w2, const float* __restrict__ b2,
                        float* __restrict__ ss1, float* __restrict__ ss2) {
    int t = blockIdx.x * 256 + threadIdx.x;          // 0..8191
    int which = t >> 12;
    int rem = t & 4095;
    int b = rem >> 9;
    int col = rem & 511;
    const float* w = which ? w2 : w1;
    const float* bb = which ? b2 : b1;
    const float* tr = te + b * C_;
    float acc = bb[col];
    for (int k = 0; k < C_; ++k) acc += tr[k] * w[k * 512 + col];
    (which ? ss2 : ss1)[b * 512 + col] = acc;
}

// ---------- weight prep: bf16 [N][K] transposes, qkv bias, bias_full ---------
__global__ void prep_k(const float* __restrict__ qw, const float* __restrict__ kw,
                       const float* __restrict__ vw, const float* __restrict__ ow,
                       const float* __restrict__ f1w, const float* __restrict__ f2w,
                       const float* __restrict__ qb, const float* __restrict__ kb,
                       const float* __restrict__ vb, const float* __restrict__ bt,
                       unsigned short* __restrict__ qkvT, unsigned short* __restrict__ oT,
                       unsigned short* __restrict__ f1T, unsigned short* __restrict__ f2T,
                       float* __restrict__ qkvB, float* __restrict__ bias_full) {
    int t = blockIdx.x * 256 + threadIdx.x;
    if (t < 196608) {                       // qkvT [768][256]
        int n = t >> 8, k = t & 255;
        const float* w = n < 256 ? qw : (n < 512 ? kw : vw);
        qkvT[t] = f2b(w[k * 256 + (n & 255)]);
    } else if (t < 262144) {                // oT [256][256]
        int i = t - 196608; int n = i >> 8, k = i & 255;
        oT[i] = f2b(ow[k * 256 + n]);
    } else if (t < 524288) {                // f1T [1024][256]
        int i = t - 262144; int n = i >> 8, k = i & 255;
        f1T[i] = f2b(f1w[k * 1024 + n]);
    } else if (t < 786432) {                // f2T [256][1024]
        int i = t - 524288; int n = i >> 10, k = i & 1023;
        f2T[i] = f2b(f2w[k * 256 + n]);
    } else if (t < 787200) {                // qkv bias [768]
        int i = t - 786432;
        qkvB[i] = i < 256 ? qb[i] : (i < 512 ? kb[i - 256] : vb[i - 512]);
    } else if (t < 787200 + 32768) {        // bias_full [8][64][64]
        int i = t - 787200;
        int head = i >> 12, qk = i & 4095;
        int q = qk >> 6, k = qk & 63;
        int qh = q >> 3, qw2 = q & 7, kh = k >> 3, kw2 = k & 7;
        bias_full[i] = bt[((qh - kh + 7) * 15 + (qw2 - kw2 + 7)) * 8 + head];
    }
}

// ------ LN + modulate + shift + window partition: one wave per token ---------
__global__ __launch_bounds__(256) void ln_win_k(const float* __restrict__ x,
                                                const float* __restrict__ ss,
                                                unsigned short* __restrict__ xw) {
    int t = blockIdx.x * 4 + (threadIdx.x >> 6);     // token 0..32767
    int lane = threadIdx.x & 63;
    int b = t >> 12, rem = t & 4095;
    int hg = rem >> 6, wg = rem & 63;
    int hs = (hg + SH_) & 63, wsrc = (wg + SH_) & 63;
    size_t src = ((size_t)b << 12) + (hs << 6) + wsrc;
    float4 v = *(const float4*)&x[src * C_ + lane * 4];
    float s = v.x + v.y + v.z + v.w;
    float s2 = v.x * v.x + v.y * v.y + v.z * v.z + v.w * v.w;
#pragma unroll
    for (int m = 1; m < 64; m <<= 1) { s += __shfl_xor(s, m); s2 += __shfl_xor(s2, m); }
    float mu = s * (1.f / 256.f);
    float rstd = rsqrtf(s2 * (1.f / 256.f) - mu * mu + LN_EPS);
    float4 sc = *(const float4*)&ss[b * 512 + lane * 4];
    float4 sh = *(const float4*)&ss[b * 512 + 256 + lane * 4];
    int win = (b << 6) + ((hg >> 3) << 3) + (wg >> 3);
    int pos = ((hg & 7) << 3) + (wg & 7);
    ushort4 pk;
    pk.x = f2b((v.x - mu) * rstd * (1.f + sc.x) + sh.x);
    pk.y = f2b((v.y - mu) * rstd * (1.f + sc.y) + sh.y);
    pk.z = f2b((v.z - mu) * rstd * (1.f + sc.z) + sh.z);
    pk.w = f2b((v.w - mu) * rstd * (1.f + sc.w) + sh.w);
    *(ushort4*)(xw + (size_t)(win * 64 + pos) * C_ + lane * 4) = pk;
}

// --------------- bf16 MFMA GEMM, 128x128 tile, BK=64 (2x32), swapped ---------
// 1D grid with XCD-affine decode (see R5). acc = mfma(B_frag, A_frag):
// lane l16 -> M row, quad*4+r -> 4 consecutive N.
template <int KDIM, int MODE, int NT>
__global__ __launch_bounds__(256) void gemm_bf16_k(
    const unsigned short* __restrict__ A, const unsigned short* __restrict__ Bt,
    const float* __restrict__ bias, const float* __restrict__ res,
    void* __restrict__ Cout, int Nout) {
    __shared__ __align__(16) unsigned short As[2][128 * 32];
    __shared__ __align__(16) unsigned short Bs[2][128 * 32];
    const int blk = blockIdx.x;
    const int xcd = blk & 7;
    const int idx = blk >> 3;
    const int mt = xcd + ((idx / NT) << 3);
    const int nt = idx % NT;
    const int bm = mt * 128, bn = nt * 128;
    const int tid = threadIdx.x;
    const int w = tid >> 6, lane = tid & 63;
    const int quad = lane >> 4, l16 = lane & 15;
    const int wm = (w >> 1) * 64, wn = (w & 1) * 64;
    const int srow = lane >> 2, scol = (lane & 3) * 8;

    f32x4 acc[4][4] = {};

    for (int k0 = 0; k0 < KDIM; k0 += 64) {
        if (k0) __syncthreads();
#pragma unroll
        for (int h = 0; h < 2; ++h) {
#pragma unroll
            for (int j = 0; j < 2; ++j) {
                int r = j * 64 + w * 16 + srow;
                const unsigned short* ga = A + (size_t)(bm + r) * KDIM + k0 + h * 32 + scol;
                unsigned short* la = &As[h][j * 2048 + w * 512 + lane * 8];
                __builtin_amdgcn_global_load_lds(
                    (const __attribute__((address_space(1))) void*)ga,
                    (__attribute__((address_space(3))) void*)la, 16, 0, 0);
                const unsigned short* gb = Bt + (size_t)(bn + r) * KDIM + k0 + h * 32 + scol;
                unsigned short* lb = &Bs[h][j * 2048 + w * 512 + lane * 8];
                __builtin_amdgcn_global_load_lds(
                    (const __attribute__((address_space(1))) void*)gb,
                    (__attribute__((address_space(3))) void*)lb, 16, 0, 0);
            }
        }
        __syncthreads();
#pragma unroll
        for (int h = 0; h < 2; ++h) {
            bf16x8 af[4], bfr[4];
#pragma unroll
            for (int i = 0; i < 4; ++i)
                af[i] = *(const bf16x8*)&As[h][(wm + i * 16 + l16) * 32 + quad * 8];
#pragma unroll
            for (int j = 0; j < 4; ++j)
                bfr[j] = *(const bf16x8*)&Bs[h][(wn + j * 16 + l16) * 32 + quad * 8];
#pragma unroll
            for (int i = 0; i < 4; ++i)
#pragma unroll
                for (int j = 0; j < 4; ++j)
                    acc[i][j] = __builtin_amdgcn_mfma_f32_16x16x32_bf16(
                        bfr[j], af[i], acc[i][j], 0, 0, 0);
        }
    }

#pragma unroll
    for (int i = 0; i < 4; ++i) {
        const int row = bm + wm + i * 16 + l16;
        size_t rowbase = 0;
        if (MODE == 0) {
            int win = row >> 6, pos = row & 63;
            rowbase = (size_t)win * 16384 + pos * 32;
        } else if (MODE == 1) {
            int win = row >> 6, pos = row & 63;
            int b = win >> 6, wh = (win >> 3) & 7, ww = win & 7;
            int hg = (wh << 3) + (pos >> 3), wg = (ww << 3) + (pos & 7);
            int hd = (hg + SH_) & 63, wd = (wg + SH_) & 63;
            rowbase = (((size_t)b << 12) + (hd << 6) + wd) * C_;
        } else {
            rowbase = (size_t)row * Nout;
        }
#pragma unroll
        for (int j = 0; j < 4; ++j) {
            const int col = bn + wn + j * 16 + quad * 4;
            float4 bv = *(const float4*)&bias[col];
            float v0 = acc[i][j][0] + bv.x, v1 = acc[i][j][1] + bv.y;
            float v2 = acc[i][j][2] + bv.z, v3 = acc[i][j][3] + bv.w;
            if (MODE == 0) {
                int which = col >> 8, head = (col >> 5) & 7, dc = col & 31;
                ushort4 pk = {f2b(v0), f2b(v1), f2b(v2), f2b(v3)};
                *(ushort4*)((unsigned short*)Cout + (size_t)which * SL_ + rowbase +
                            head * 2048 + dc) = pk;
            } else if (MODE == 1) {
                float4 rv = *(const float4*)&res[rowbase + col];
                float4 ov = {v0 + rv.x, v1 + rv.y, v2 + rv.z, v3 + rv.w};
                *(float4*)&((float*)Cout)[rowbase + col] = ov;
            } else {
                float4 rv = *(const float4*)&res[rowbase + col];
                float4 ov = {v0 + rv.x, v1 + rv.y, v2 + rv.z, v3 + rv.w};
                *(float4*)&((float*)Cout)[rowbase + col] = ov;
            }
        }
    }
}

// -------- Fused LN2 + FFN1 + GELU + FFN2 + residual, one block per 64 rows ---
// Xs: LN2(x1) tile in chunked A-layout [kchunk][row][32]. Loop 8 chunks of
// 128 FFN1-cols: h = gelu(Xs @ f1T_chunk^T + b1) -> Hs (dbuf), then
// acc2 += Hs @ f2T_chunk^T. Weights (0.5 MB each) read per-fragment from L2.
__global__ __launch_bounds__(256) void ffn_fused_k(
    const float* __restrict__ x1, const float* __restrict__ ss2,
    const unsigned short* __restrict__ f1T, const unsigned short* __restrict__ f2T,
    const float* __restrict__ f1b, const float* __restrict__ f2bb,
    float* __restrict__ out) {
    __shared__ __align__(16) unsigned short Xs[8][64][32];     // 32 KB
    __shared__ __align__(16) unsigned short Hs[2][4][64][32];  // 32 KB
    const int bm = blockIdx.x << 6;
    const int tid = threadIdx.x;
    const int w = tid >> 6, lane = tid & 63;
    const int quad = lane >> 4, l16 = lane & 15;

    // ---- Phase 0: LN2 + modulate -> Xs ----
    {
        const int row = tid >> 2;            // 0..63
        const int cseg = (tid & 3) << 6;     // 0,64,128,192
        const int b = bm >> 12;
        const float* xr = x1 + (size_t)(bm + row) * C_ + cseg;
        float4 v[16];
        float s = 0.f, s2 = 0.f;
#pragma unroll
        for (int i = 0; i < 16; ++i) {
            v[i] = *(const float4*)(xr + i * 4);
            s  += v[i].x + v[i].y + v[i].z + v[i].w;
            s2 += v[i].x * v[i].x + v[i].y * v[i].y + v[i].z * v[i].z + v[i].w * v[i].w;
        }
        s += __shfl_xor(s, 1); s2 += __shfl_xor(s2, 1);
        s += __shfl_xor(s, 2); s2 += __shfl_xor(s2, 2);
        float mu = s * (1.f / 256.f);
        float rstd = rsqrtf(s2 * (1.f / 256.f) - mu * mu + LN_EPS);
        const float* scp = ss2 + b * 512 + cseg;
        const float* shp = ss2 + b * 512 + 256 + cseg;
#pragma unroll
        for (int i = 0; i < 16; ++i) {
            float4 sc = *(const float4*)(scp + i * 4);
            float4 sh = *(const float4*)(shp + i * 4);
            int c0 = cseg + i * 4;
            unsigned int p0 = (unsigned int)f2b((v[i].x - mu) * rstd * (1.f + sc.x) + sh.x) |
                              ((unsigned int)f2b((v[i].y - mu) * rstd * (1.f + sc.y) + sh.y) << 16);
            unsigned int p1 = (unsigned int)f2b((v[i].z - mu) * rstd * (1.f + sc.z) + sh.z) |
                              ((unsigned int)f2b((v[i].w - mu) * rstd * (1.f + sc.w) + sh.w) << 16);
            unsigned int* xu = (unsigned int*)&Xs[c0 >> 5][row][c0 & 31];
            xu[0] = p0; xu[1] = p1;
        }
    }
    __syncthreads();

    f32x4 acc2[4][4] = {};

    for (int c = 0; c < 8; ++c) {
        // FFN1 chunk: h[64][128], wave w owns local n1 cols w*32..w*32+31
        f32x4 acc1[4][2] = {};
#pragma unroll
        for (int ks = 0; ks < 8; ++ks) {
            bf16x8 af[4], bfr[2];
#pragma unroll
            for (int i = 0; i < 4; ++i)
                af[i] = *(const bf16x8*)&Xs[ks][i * 16 + l16][quad * 8];
#pragma unroll
            for (int j = 0; j < 2; ++j)
                bfr[j] = *(const bf16x8*)(f1T +
                    (size_t)((c << 7) + (w << 5) + (j << 4) + l16) * 256 + (ks << 5) + quad * 8);
#pragma unroll
            for (int i = 0; i < 4; ++i)
#pragma unroll
                for (int j = 0; j < 2; ++j)
                    acc1[i][j] = __builtin_amdgcn_mfma_f32_16x16x32_bf16(
                        bfr[j], af[i], acc1[i][j], 0, 0, 0);
        }
        // bias + gelu -> Hs[c&1][w]
#pragma unroll
        for (int i = 0; i < 4; ++i)
#pragma unroll
            for (int j = 0; j < 2; ++j) {
                int ncol = (w << 5) + (j << 4) + (quad << 2);   // local n1
                float4 bv = *(const float4*)(f1b + (c << 7) + ncol);
                unsigned int p0 = (unsigned int)f2b(gelu_f(acc1[i][j][0] + bv.x)) |
                                  ((unsigned int)f2b(gelu_f(acc1[i][j][1] + bv.y)) << 16);
                unsigned int p1 = (unsigned int)f2b(gelu_f(acc1[i][j][2] + bv.z)) |
                                  ((unsigned int)f2b(gelu_f(acc1[i][j][3] + bv.w)) << 16);
                unsigned int* hu = (unsigned int*)&Hs[c & 1][w][i * 16 + l16][(j << 4) + (quad << 2)];
                hu[0] = p0; hu[1] = p1;
            }
        __syncthreads();
        // FFN2 accumulate over this chunk's 128 k-values
#pragma unroll
        for (int kst = 0; kst < 4; ++kst) {
            bf16x8 af[4], bfr[4];
#pragma unroll
            for (int i = 0; i < 4; ++i)
                af[i] = *(const bf16x8*)&Hs[c & 1][kst][i * 16 + l16][quad * 8];
#pragma unroll
            for (int j = 0; j < 4; ++j)
                bfr[j] = *(const bf16x8*)(f2T +
                    (size_t)((w << 6) + (j << 4) + l16) * 1024 + (c << 7) + (kst << 5) + quad * 8);
#pragma unroll
            for (int i = 0; i < 4; ++i)
#pragma unroll
                for (int j = 0; j < 4; ++j)
                    acc2[i][j] = __builtin_amdgcn_mfma_f32_16x16x32_bf16(
                        bfr[j], af[i], acc2[i][j], 0, 0, 0);
        }
    }

    // epilogue: out = acc2 + b2 + x1 (residual); wave w -> cols w*64..w*64+63
#pragma unroll
    for (int i = 0; i < 4; ++i) {
        int row = bm + i * 16 + l16;
        size_t rb = (size_t)row * C_;
#pragma unroll
        for (int j = 0; j < 4; ++j) {
            int col = (w << 6) + (j << 4) + (quad << 2);
            float4 bv = *(const float4*)(f2bb + col);
            float4 rv = *(const float4*)(x1 + rb + col);
            float4 ov = {acc2[i][j][0] + bv.x + rv.x, acc2[i][j][1] + bv.y + rv.y,
                         acc2[i][j][2] + bv.z + rv.z, acc2[i][j][3] + bv.w + rv.w};
            *(float4*)(out + rb + col) = ov;
        }
    }
}

// ------------- MFMA window attention: one wave per (window, head) ------------
__global__ __launch_bounds__(256) void attn_mfma_k(
    const unsigned short* __restrict__ qkv, const float* __restrict__ bias_full,
    unsigned short* __restrict__ attn_out) {
    __shared__ __align__(16) unsigned short Pb[4][64 * 66];
    __shared__ __align__(16) unsigned short Vt[4][32 * 66];
    const int w = threadIdx.x >> 6, lane = threadIdx.x & 63;
    const int wh = blockIdx.x * 4 + w;        // 0..4095
    const int win = wh >> 3, head = wh & 7;
    const int quad = lane >> 4, l16 = lane & 15;

    const unsigned short* qp = qkv + (size_t)win * 16384 + head * 2048;
    const unsigned short* kp = qp + SL_;
    const unsigned short* vp = qp + 2 * (size_t)SL_;

    // stage V transposed: Vt[d][pos]
    {
        const uint4* v4 = (const uint4*)(vp + lane * 32);
        unsigned short* dst = &Vt[w][0];
#pragma unroll
        for (int c = 0; c < 4; ++c) {
            uint4 u = v4[c];
            unsigned int uu[4] = {u.x, u.y, u.z, u.w};
#pragma unroll
            for (int p = 0; p < 4; ++p) {
                int d0 = c * 8 + p * 2;
                dst[d0 * 66 + lane] = (unsigned short)(uu[p] & 0xffff);
                dst[(d0 + 1) * 66 + lane] = (unsigned short)(uu[p] >> 16);
            }
        }
    }

    bf16x8 qf[4], kf[4];
#pragma unroll
    for (int i = 0; i < 4; ++i) {
        qf[i] = *(const bf16x8*)(qp + (i * 16 + l16) * 32 + quad * 8);
        kf[i] = *(const bf16x8*)(kp + (i * 16 + l16) * 32 + quad * 8);
    }

    f32x4 s[4][4] = {};
#pragma unroll
    for (int i = 0; i < 4; ++i)
#pragma unroll
        for (int j = 0; j < 4; ++j)
            s[i][j] = __builtin_amdgcn_mfma_f32_16x16x32_bf16(qf[i], kf[j], s[i][j], 0, 0, 0);

    const float scale = 0.17677669529663687f;
    const float* bf = bias_full + head * 4096;
    float rs[4][4];
#pragma unroll
    for (int i = 0; i < 4; ++i) {
#pragma unroll
        for (int r = 0; r < 4; ++r) {
            int row = i * 16 + quad * 4 + r;
            float acc = 0.f;
#pragma unroll
            for (int j = 0; j < 4; ++j) {
                float e = __expf(s[i][j][r] * scale + bf[row * 64 + j * 16 + l16]);
                s[i][j][r] = e;
                acc += e;
            }
#pragma unroll
            for (int msk = 1; msk < 16; msk <<= 1) acc += __shfl_xor(acc, msk);
            rs[i][r] = 1.f / acc;
        }
    }

#pragma unroll
    for (int i = 0; i < 4; ++i)
#pragma unroll
        for (int j = 0; j < 4; ++j)
#pragma unroll
            for (int r = 0; r < 4; ++r)
                Pb[w][(i * 16 + quad * 4 + r) * 66 + j * 16 + l16] = f2b(s[i][j][r]);

    __syncthreads();

    f32x4 o[4][2] = {};
#pragma unroll
    for (int st = 0; st < 2; ++st) {
        bf16x8 bv[2];
#pragma unroll
        for (int jo = 0; jo < 2; ++jo)
            bv[jo] = *(const bf16x8*)&Vt[w][(jo * 16 + l16) * 66 + st * 32 + quad * 8];
#pragma unroll
        for (int i = 0; i < 4; ++i) {
            bf16x8 af = *(const bf16x8*)&Pb[w][(i * 16 + l16) * 66 + st * 32 + quad * 8];
#pragma unroll
            for (int jo = 0; jo < 2; ++jo)
                o[i][jo] = __builtin_amdgcn_mfma_f32_16x16x32_bf16(af, bv[jo], o[i][jo], 0, 0, 0);
        }
    }

#pragma unroll
    for (int i = 0; i < 4; ++i)
#pragma unroll
        for (int jo = 0; jo < 2; ++jo)
#pragma unroll
            for (int r = 0; r < 4; ++r) {
                int row = i * 16 + quad * 4 + r;
                int d = jo * 16 + l16;
                attn_out[((size_t)(win * 64 + row)) * C_ + head * 32 + d] =
                    f2b(o[i][jo][r] * rs[i][r]);
            }
}

extern "C" void kernel_launch(void* const* d_in, const int* in_sizes, int n_in,
                              void* d_out, int out_size, void* d_ws, size_t ws_size,
                              hipStream_t stream) {
    const float* x        = (const float*)d_in[0];
    const float* t_embed  = (const float*)d_in[1];
    const float* adaln1_w = (const float*)d_in[4];
    const float* adaln1_b = (const float*)d_in[5];
    const float* adaln2_w = (const float*)d_in[6];
    const float* adaln2_b = (const float*)d_in[7];
    const float* bt       = (const float*)d_in[8];
    const float* q_w = (const float*)d_in[9],  *q_b = (const float*)d_in[10];
    const float* k_w = (const float*)d_in[11], *k_b = (const float*)d_in[12];
    const float* v_w = (const float*)d_in[13], *v_b = (const float*)d_in[14];
    const float* o_w = (const float*)d_in[15], *o_b = (const float*)d_in[16];
    const float* f1_w = (const float*)d_in[17], *f1_b = (const float*)d_in[18];
    const float* f2_w = (const float*)d_in[19], *f2_b = (const float*)d_in[20];
    float* out = (float*)d_out;

    char* wsb = (char*)d_ws;
    float* ss1            = (float*)(wsb + 0);
    float* ss2            = (float*)(wsb + 16384);
    float* qkvB           = (float*)(wsb + 32768);
    unsigned short* qkvT  = (unsigned short*)(wsb + 36864);
    unsigned short* oT    = (unsigned short*)(wsb + 430080);
    unsigned short* f1T   = (unsigned short*)(wsb + 561152);
    unsigned short* f2T   = (unsigned short*)(wsb + 1085440);
    float* bias_full      = (float*)(wsb + 1609728);               // 131072 B
    unsigned short* xw    = (unsigned short*)(wsb + 2097152);      // [M][256] bf16
    unsigned short* qkv   = (unsigned short*)(wsb + 18874368);     // 3 x SL_ bf16
    unsigned short* attn  = (unsigned short*)(wsb + 69206016);     // [M][256] bf16
    float* x1             = (float*)(wsb + 85983232);              // [M][256] fp32

    prep_k<<<3203, 256, 0, stream>>>(q_w, k_w, v_w, o_w, f1_w, f2_w, q_b, k_b, v_b, bt,
                                     qkvT, oT, f1T, f2T, qkvB, bias_full);
    adaln_k<<<32, 256, 0, stream>>>(t_embed, adaln1_w, adaln1_b, adaln2_w, adaln2_b, ss1, ss2);
    ln_win_k<<<8192, 256, 0, stream>>>(x, ss1, xw);

    gemm_bf16_k<256, 0, 6><<<1536, 256, 0, stream>>>(xw, qkvT, qkvB, nullptr, qkv, 768);

    attn_mfma_k<<<1024, 256, 0, stream>>>(qkv, bias_full, attn);

    gemm_bf16_k<256, 1, 2><<<512, 256, 0, stream>>>(attn, oT, o_b, x, x1, 256);

    ffn_fused_k<<<512, 256, 0, stream>>>(x1, ss2, f1T, f2T, f1_b, f2_b, out);
}

// Round 7
// 290.836 us; speedup vs baseline: 1.0968x; 1.0968x over previous
//
#include <hip/hip_runtime.h>
#include <math.h>

#define WS_ 8
#define NH_ 8
#define C_ 256
#define B_ 8
#define M_ 32768            // B_*L_
#define SH_ 4               // WS_/2
#define LN_EPS 1e-5f
#define SL_ 8388608         // elements per [M,C] slot

typedef __attribute__((ext_vector_type(8))) short bf16x8;
typedef __attribute__((ext_vector_type(4))) float f32x4;

__device__ inline float b2f(unsigned short u) {
    union { unsigned int i; float f; } c; c.i = ((unsigned int)u) << 16; return c.f;
}
__device__ inline unsigned short f2b(float f) {
    union { unsigned int i; float f; } c; c.f = f;
    unsigned int u = c.i;
    return (unsigned short)((u + 0x7FFFu + ((u >> 16) & 1u)) >> 16);
}
__device__ inline float gelu_f(float x) {
    // tanh-form GELU: x * sigmoid(1.59576912*(x + 0.044715 x^3)); |err| < ~1e-3
    float t = 1.59576912160573f * (x + 0.044715f * x * x * x);
    return x / (1.f + __expf(-t));
}

// ---------------- AdaLN: ss = t_embed @ w + b --------------------------------
__global__ void adaln_k(const float* __restrict__ te,
                        const float* __restrict__ w1, const float* __restrict__ b1,
                        const float* __restrict__ w2, const float* __restrict__ b2,
                        float* __restrict__ ss1, float* __restrict__ ss2) {
    int t = blockIdx.x * 256 + threadIdx.x;          // 0..8191
    int which = t >> 12;
    int rem = t & 4095;
    int b = rem >> 9;
    int col = rem & 511;
    const float* w = which ? w2 : w1;
    const float* bb = which ? b2 : b1;
    const float* tr = te + b * C_;
    float acc = bb[col];
    for (int k = 0; k < C_; ++k) acc += tr[k] * w[k * 512 + col];
    (which ? ss2 : ss1)[b * 512 + col] = acc;
}

// ---------- weight prep: bf16 [N][K] transposes, qkv bias, bias_full ---------
__global__ void prep_k(const float* __restrict__ qw, const float* __restrict__ kw,
                       const float* __restrict__ vw, const float* __restrict__ ow,
                       const float* __restrict__ f1w, const float* __restrict__ f2w,
                       const float* __restrict__ qb, const float* __restrict__ kb,
                       const float* __restrict__ vb, const float* __restrict__ bt,
                       unsigned short* __restrict__ qkvT, unsigned short* __restrict__ oT,
                       unsigned short* __restrict__ f1T, unsigned short* __restrict__ f2T,
                       float* __restrict__ qkvB, float* __restrict__ bias_full) {
    int t = blockIdx.x * 256 + threadIdx.x;
    if (t < 196608) {                       // qkvT [768][256]
        int n = t >> 8, k = t & 255;
        const float* w = n < 256 ? qw : (n < 512 ? kw : vw);
        qkvT[t] = f2b(w[k * 256 + (n & 255)]);
    } else if (t < 262144) {                // oT [256][256]
        int i = t - 196608; int n = i >> 8, k = i & 255;
        oT[i] = f2b(ow[k * 256 + n]);
    } else if (t < 524288) {                // f1T [1024][256]
        int i = t - 262144; int n = i >> 8, k = i & 255;
        f1T[i] = f2b(f1w[k * 1024 + n]);
    } else if (t < 786432) {                // f2T [256][1024]
        int i = t - 524288; int n = i >> 10, k = i & 1023;
        f2T[i] = f2b(f2w[k * 256 + n]);
    } else if (t < 787200) {                // qkv bias [768]
        int i = t - 786432;
        qkvB[i] = i < 256 ? qb[i] : (i < 512 ? kb[i - 256] : vb[i - 512]);
    } else if (t < 787200 + 32768) {        // bias_full [8][64][64]
        int i = t - 787200;
        int head = i >> 12, qk = i & 4095;
        int q = qk >> 6, k = qk & 63;
        int qh = q >> 3, qw2 = q & 7, kh = k >> 3, kw2 = k & 7;
        bias_full[i] = bt[((qh - kh + 7) * 15 + (qw2 - kw2 + 7)) * 8 + head];
    }
}

// ------ LN + modulate + shift + window partition: one wave per token ---------
__global__ __launch_bounds__(256) void ln_win_k(const float* __restrict__ x,
                                                const float* __restrict__ ss,
                                                unsigned short* __restrict__ xw) {
    int t = blockIdx.x * 4 + (threadIdx.x >> 6);     // token 0..32767
    int lane = threadIdx.x & 63;
    int b = t >> 12, rem = t & 4095;
    int hg = rem >> 6, wg = rem & 63;
    int hs = (hg + SH_) & 63, wsrc = (wg + SH_) & 63;
    size_t src = ((size_t)b << 12) + (hs << 6) + wsrc;
    float4 v = *(const float4*)&x[src * C_ + lane * 4];
    float s = v.x + v.y + v.z + v.w;
    float s2 = v.x * v.x + v.y * v.y + v.z * v.z + v.w * v.w;
#pragma unroll
    for (int m = 1; m < 64; m <<= 1) { s += __shfl_xor(s, m); s2 += __shfl_xor(s2, m); }
    float mu = s * (1.f / 256.f);
    float rstd = rsqrtf(s2 * (1.f / 256.f) - mu * mu + LN_EPS);
    float4 sc = *(const float4*)&ss[b * 512 + lane * 4];
    float4 sh = *(const float4*)&ss[b * 512 + 256 + lane * 4];
    int win = (b << 6) + ((hg >> 3) << 3) + (wg >> 3);
    int pos = ((hg & 7) << 3) + (wg & 7);
    ushort4 pk;
    pk.x = f2b((v.x - mu) * rstd * (1.f + sc.x) + sh.x);
    pk.y = f2b((v.y - mu) * rstd * (1.f + sc.y) + sh.y);
    pk.z = f2b((v.z - mu) * rstd * (1.f + sc.z) + sh.z);
    pk.w = f2b((v.w - mu) * rstd * (1.f + sc.w) + sh.w);
    *(ushort4*)(xw + (size_t)(win * 64 + pos) * C_ + lane * 4) = pk;
}

// ---------------- LN + modulate: one wave per token --------------------------
__global__ __launch_bounds__(256) void ln_k(const float* __restrict__ x,
                                            const float* __restrict__ ss,
                                            unsigned short* __restrict__ y_out) {
    int t = blockIdx.x * 4 + (threadIdx.x >> 6);
    int lane = threadIdx.x & 63;
    int b = t >> 12;
    float4 v = *(const float4*)&x[(size_t)t * C_ + lane * 4];
    float s = v.x + v.y + v.z + v.w;
    float s2 = v.x * v.x + v.y * v.y + v.z * v.z + v.w * v.w;
#pragma unroll
    for (int m = 1; m < 64; m <<= 1) { s += __shfl_xor(s, m); s2 += __shfl_xor(s2, m); }
    float mu = s * (1.f / 256.f);
    float rstd = rsqrtf(s2 * (1.f / 256.f) - mu * mu + LN_EPS);
    float4 sc = *(const float4*)&ss[b * 512 + lane * 4];
    float4 sh = *(const float4*)&ss[b * 512 + 256 + lane * 4];
    ushort4 pk;
    pk.x = f2b((v.x - mu) * rstd * (1.f + sc.x) + sh.x);
    pk.y = f2b((v.y - mu) * rstd * (1.f + sc.y) + sh.y);
    pk.z = f2b((v.z - mu) * rstd * (1.f + sc.z) + sh.z);
    pk.w = f2b((v.w - mu) * rstd * (1.f + sc.w) + sh.w);
    *(ushort4*)(y_out + (size_t)t * C_ + lane * 4) = pk;
}

// --------------- bf16 MFMA GEMM, 128x128 tile, BK=64 (2x32), swapped ---------
// XCD-affine 1D grid (R5). LDS XOR-swizzle: logical 16B chunk q of row r is
// stored at phys chunk q ^ ((r>>1)&3). Staging permutes the GLOBAL source
// chunk per lane (same 64B line -> coalescing intact; global_load_lds dest
// stays lane-contiguous); frag reads apply quad ^ ((l16>>1)&3) -> 2-way
// conflicts instead of 8-way. acc = mfma(B_frag, A_frag).
template <int KDIM, int MODE, int NT>
__global__ __launch_bounds__(256, 4) void gemm_bf16_k(
    const unsigned short* __restrict__ A, const unsigned short* __restrict__ Bt,
    const float* __restrict__ bias, const float* __restrict__ res,
    void* __restrict__ Cout, int Nout) {
    __shared__ __align__(16) unsigned short As[2][128 * 32];
    __shared__ __align__(16) unsigned short Bs[2][128 * 32];
    const int blk = blockIdx.x;
    const int xcd = blk & 7;
    const int idx = blk >> 3;
    const int mt = xcd + ((idx / NT) << 3);
    const int nt = idx % NT;
    const int bm = mt * 128, bn = nt * 128;
    const int tid = threadIdx.x;
    const int w = tid >> 6, lane = tid & 63;
    const int quad = lane >> 4, l16 = lane & 15;
    const int wm = (w >> 1) * 64, wn = (w & 1) * 64;
    const int srow = lane >> 2;
    const int qlog = ((lane & 3) ^ ((lane >> 3) & 3)) << 3;   // swizzled src chunk
    const int rsw = ((l16 >> 1) & 3) << 3;                    // read-side swizzle

    f32x4 acc[4][4] = {};

    for (int k0 = 0; k0 < KDIM; k0 += 64) {
        if (k0) __syncthreads();
#pragma unroll
        for (int h = 0; h < 2; ++h) {
#pragma unroll
            for (int j = 0; j < 2; ++j) {
                int r = j * 64 + w * 16 + srow;
                const unsigned short* ga = A + (size_t)(bm + r) * KDIM + k0 + h * 32 + qlog;
                unsigned short* la = &As[h][j * 2048 + w * 512 + lane * 8];
                __builtin_amdgcn_global_load_lds(
                    (const __attribute__((address_space(1))) void*)ga,
                    (__attribute__((address_space(3))) void*)la, 16, 0, 0);
                const unsigned short* gb = Bt + (size_t)(bn + r) * KDIM + k0 + h * 32 + qlog;
                unsigned short* lb = &Bs[h][j * 2048 + w * 512 + lane * 8];
                __builtin_amdgcn_global_load_lds(
                    (const __attribute__((address_space(1))) void*)gb,
                    (__attribute__((address_space(3))) void*)lb, 16, 0, 0);
            }
        }
        __syncthreads();
#pragma unroll
        for (int h = 0; h < 2; ++h) {
            bf16x8 af[4], bfr[4];
#pragma unroll
            for (int i = 0; i < 4; ++i)
                af[i] = *(const bf16x8*)&As[h][(wm + i * 16 + l16) * 32 + ((quad << 3) ^ rsw)];
#pragma unroll
            for (int j = 0; j < 4; ++j)
                bfr[j] = *(const bf16x8*)&Bs[h][(wn + j * 16 + l16) * 32 + ((quad << 3) ^ rsw)];
#pragma unroll
            for (int i = 0; i < 4; ++i)
#pragma unroll
                for (int j = 0; j < 4; ++j)
                    acc[i][j] = __builtin_amdgcn_mfma_f32_16x16x32_bf16(
                        bfr[j], af[i], acc[i][j], 0, 0, 0);
        }
    }

#pragma unroll
    for (int i = 0; i < 4; ++i) {
        const int row = bm + wm + i * 16 + l16;
        size_t rowbase = 0;
        if (MODE == 0) {
            int win = row >> 6, pos = row & 63;
            rowbase = (size_t)win * 16384 + pos * 32;
        } else if (MODE == 1) {
            int win = row >> 6, pos = row & 63;
            int b = win >> 6, wh = (win >> 3) & 7, ww = win & 7;
            int hg = (wh << 3) + (pos >> 3), wg = (ww << 3) + (pos & 7);
            int hd = (hg + SH_) & 63, wd = (wg + SH_) & 63;
            rowbase = (((size_t)b << 12) + (hd << 6) + wd) * C_;
        } else {
            rowbase = (size_t)row * Nout;
        }
#pragma unroll
        for (int j = 0; j < 4; ++j) {
            const int col = bn + wn + j * 16 + quad * 4;
            float4 bv = *(const float4*)&bias[col];
            float v0 = acc[i][j][0] + bv.x, v1 = acc[i][j][1] + bv.y;
            float v2 = acc[i][j][2] + bv.z, v3 = acc[i][j][3] + bv.w;
            if (MODE == 0) {
                int which = col >> 8, head = (col >> 5) & 7, dc = col & 31;
                ushort4 pk = {f2b(v0), f2b(v1), f2b(v2), f2b(v3)};
                *(ushort4*)((unsigned short*)Cout + (size_t)which * SL_ + rowbase +
                            head * 2048 + dc) = pk;
            } else if (MODE == 1) {
                float4 rv = *(const float4*)&res[rowbase + col];
                float4 ov = {v0 + rv.x, v1 + rv.y, v2 + rv.z, v3 + rv.w};
                *(float4*)&((float*)Cout)[rowbase + col] = ov;
            } else if (MODE == 2) {
                ushort4 pk = {f2b(gelu_f(v0)), f2b(gelu_f(v1)),
                              f2b(gelu_f(v2)), f2b(gelu_f(v3))};
                *(ushort4*)((unsigned short*)Cout + rowbase + col) = pk;
            } else {
                float4 rv = *(const float4*)&res[rowbase + col];
                float4 ov = {v0 + rv.x, v1 + rv.y, v2 + rv.z, v3 + rv.w};
                *(float4*)&((float*)Cout)[rowbase + col] = ov;
            }
        }
    }
}

// ------------- MFMA window attention: one wave per (window, head) ------------
__global__ __launch_bounds__(256) void attn_mfma_k(
    const unsigned short* __restrict__ qkv, const float* __restrict__ bias_full,
    unsigned short* __restrict__ attn_out) {
    __shared__ __align__(16) unsigned short Pb[4][64 * 66];
    __shared__ __align__(16) unsigned short Vt[4][32 * 66];
    const int w = threadIdx.x >> 6, lane = threadIdx.x & 63;
    const int wh = blockIdx.x * 4 + w;        // 0..4095
    const int win = wh >> 3, head = wh & 7;
    const int quad = lane >> 4, l16 = lane & 15;

    const unsigned short* qp = qkv + (size_t)win * 16384 + head * 2048;
    const unsigned short* kp = qp + SL_;
    const unsigned short* vp = qp + 2 * (size_t)SL_;

    // stage V transposed: Vt[d][pos]
    {
        const uint4* v4 = (const uint4*)(vp + lane * 32);
        unsigned short* dst = &Vt[w][0];
#pragma unroll
        for (int c = 0; c < 4; ++c) {
            uint4 u = v4[c];
            unsigned int uu[4] = {u.x, u.y, u.z, u.w};
#pragma unroll
            for (int p = 0; p < 4; ++p) {
                int d0 = c * 8 + p * 2;
                dst[d0 * 66 + lane] = (unsigned short)(uu[p] & 0xffff);
                dst[(d0 + 1) * 66 + lane] = (unsigned short)(uu[p] >> 16);
            }
        }
    }

    bf16x8 qf[4], kf[4];
#pragma unroll
    for (int i = 0; i < 4; ++i) {
        qf[i] = *(const bf16x8*)(qp + (i * 16 + l16) * 32 + quad * 8);
        kf[i] = *(const bf16x8*)(kp + (i * 16 + l16) * 32 + quad * 8);
    }

    f32x4 s[4][4] = {};
#pragma unroll
    for (int i = 0; i < 4; ++i)
#pragma unroll
        for (int j = 0; j < 4; ++j)
            s[i][j] = __builtin_amdgcn_mfma_f32_16x16x32_bf16(qf[i], kf[j], s[i][j], 0, 0, 0);

    const float scale = 0.17677669529663687f;
    const float* bf = bias_full + head * 4096;
    float rs[4][4];
#pragma unroll
    for (int i = 0; i < 4; ++i) {
#pragma unroll
        for (int r = 0; r < 4; ++r) {
            int row = i * 16 + quad * 4 + r;
            float acc = 0.f;
#pragma unroll
            for (int j = 0; j < 4; ++j) {
                float e = __expf(s[i][j][r] * scale + bf[row * 64 + j * 16 + l16]);
                s[i][j][r] = e;
                acc += e;
            }
#pragma unroll
            for (int msk = 1; msk < 16; msk <<= 1) acc += __shfl_xor(acc, msk);
            rs[i][r] = 1.f / acc;
        }
    }

#pragma unroll
    for (int i = 0; i < 4; ++i)
#pragma unroll
        for (int j = 0; j < 4; ++j)
#pragma unroll
            for (int r = 0; r < 4; ++r)
                Pb[w][(i * 16 + quad * 4 + r) * 66 + j * 16 + l16] = f2b(s[i][j][r]);

    __syncthreads();

    f32x4 o[4][2] = {};
#pragma unroll
    for (int st = 0; st < 2; ++st) {
        bf16x8 bv[2];
#pragma unroll
        for (int jo = 0; jo < 2; ++jo)
            bv[jo] = *(const bf16x8*)&Vt[w][(jo * 16 + l16) * 66 + st * 32 + quad * 8];
#pragma unroll
        for (int i = 0; i < 4; ++i) {
            bf16x8 af = *(const bf16x8*)&Pb[w][(i * 16 + l16) * 66 + st * 32 + quad * 8];
#pragma unroll
            for (int jo = 0; jo < 2; ++jo)
                o[i][jo] = __builtin_amdgcn_mfma_f32_16x16x32_bf16(af, bv[jo], o[i][jo], 0, 0, 0);
        }
    }

#pragma unroll
    for (int i = 0; i < 4; ++i)
#pragma unroll
        for (int jo = 0; jo < 2; ++jo)
#pragma unroll
            for (int r = 0; r < 4; ++r) {
                int row = i * 16 + quad * 4 + r;
                int d = jo * 16 + l16;
                attn_out[((size_t)(win * 64 + row)) * C_ + head * 32 + d] =
                    f2b(o[i][jo][r] * rs[i][r]);
            }
}

extern "C" void kernel_launch(void* const* d_in, const int* in_sizes, int n_in,
                              void* d_out, int out_size, void* d_ws, size_t ws_size,
                              hipStream_t stream) {
    const float* x        = (const float*)d_in[0];
    const float* t_embed  = (const float*)d_in[1];
    const float* adaln1_w = (const float*)d_in[4];
    const float* adaln1_b = (const float*)d_in[5];
    const float* adaln2_w = (const float*)d_in[6];
    const float* adaln2_b = (const float*)d_in[7];
    const float* bt       = (const float*)d_in[8];
    const float* q_w = (const float*)d_in[9],  *q_b = (const float*)d_in[10];
    const float* k_w = (const float*)d_in[11], *k_b = (const float*)d_in[12];
    const float* v_w = (const float*)d_in[13], *v_b = (const float*)d_in[14];
    const float* o_w = (const float*)d_in[15], *o_b = (const float*)d_in[16];
    const float* f1_w = (const float*)d_in[17], *f1_b = (const float*)d_in[18];
    const float* f2_w = (const float*)d_in[19], *f2_b = (const float*)d_in[20];
    float* out = (float*)d_out;

    char* wsb = (char*)d_ws;
    float* ss1            = (float*)(wsb + 0);
    float* ss2            = (float*)(wsb + 16384);
    float* qkvB           = (float*)(wsb + 32768);
    unsigned short* qkvT  = (unsigned short*)(wsb + 36864);
    unsigned short* oT    = (unsigned short*)(wsb + 430080);
    unsigned short* f1T   = (unsigned short*)(wsb + 561152);
    unsigned short* f2T   = (unsigned short*)(wsb + 1085440);
    float* bias_full      = (float*)(wsb + 1609728);               // 131072 B
    unsigned short* xw    = (unsigned short*)(wsb + 2097152);      // [M][256] bf16
    unsigned short* qkv   = (unsigned short*)(wsb + 18874368);     // 3 x SL_ bf16
    unsigned short* attn  = (unsigned short*)(wsb + 69206016);     // [M][256] bf16
    unsigned short* xn2   = xw;                                    // reuse
    unsigned short* hbuf  = qkv;                                   // reuse (67.1 MB)
    float* x1             = (float*)(wsb + 85983232);              // [M][256] fp32

    prep_k<<<3203, 256, 0, stream>>>(q_w, k_w, v_w, o_w, f1_w, f2_w, q_b, k_b, v_b, bt,
                                     qkvT, oT, f1T, f2T, qkvB, bias_full);
    adaln_k<<<32, 256, 0, stream>>>(t_embed, adaln1_w, adaln1_b, adaln2_w, adaln2_b, ss1, ss2);
    ln_win_k<<<8192, 256, 0, stream>>>(x, ss1, xw);

    gemm_bf16_k<256, 0, 6><<<1536, 256, 0, stream>>>(xw, qkvT, qkvB, nullptr, qkv, 768);

    attn_mfma_k<<<1024, 256, 0, stream>>>(qkv, bias_full, attn);

    gemm_bf16_k<256, 1, 2><<<512, 256, 0, stream>>>(attn, oT, o_b, x, x1, 256);
    ln_k<<<8192, 256, 0, stream>>>(x1, ss2, xn2);
    gemm_bf16_k<256, 2, 8><<<2048, 256, 0, stream>>>(xn2, f1T, f1_b, nullptr, hbuf, 1024);
    gemm_bf16_k<1024, 3, 2><<<512, 256, 0, stream>>>(hbuf, f2T, f2_b, x1, out, 256);
}